// Round 1
// baseline (1057.283 us; speedup 1.0000x reference)
//
#include <hip/hip_runtime.h>
#include <cstddef>

// ---------------- problem constants ----------------
#define NB 16      // batch
#define NC 256     // channels
#define NH 32
#define NW 32
#define NK 81      // 9x9 displacements

// workspace float offsets
#define WS_FG      0u                         // [16,256,32,32]
#define WS_MRES    4194304u                   // [16,81,32,32]
#define WS_SMASK   5521408u                   // [16,81,32,32]
#define WS_ANUM    6848512u                   // [16,32,32]
#define WS_CONST   6864896u                   // label[81], m[81], sw[81], step, rw, src[3], reg[3]

__device__ __forceinline__ float4 ld4(const float* p) { return *reinterpret_cast<const float4*>(p); }
__device__ __forceinline__ void st4(float* p, float4 v) { *reinterpret_cast<float4*>(p) = v; }

// ---------------- constants / distance map ----------------
__global__ void k_const(const float* lw, const float* mw, const float* sww,
                        const float* lsl, const float* fr, float* cst) {
    int tid = threadIdx.x;
    if (tid < 81) {
        int dy = tid / 9, dx = tid % 9;
        float dist = sqrtf((float)((dy - 4) * (dy - 4) + (dx - 4) * (dx - 4)));
        float lab = 0.f, mm = 0.f, ss = 0.f;
        for (int d = 0; d < 10; d++) {
            float diff = dist * 2.f - (float)d;
            float bv = (d < 9) ? fmaxf(0.f, 1.f - fabsf(diff))
                               : fminf(fmaxf(1.f + diff, 0.f), 1.f);
            lab += bv * lw[d];
            mm  += bv * mw[d];
            ss  += bv * sww[d];
        }
        cst[tid]       = lab;
        cst[81 + tid]  = 1.f / (1.f + expf(-mm));
        cst[162 + tid] = ss;
    } else if (tid == 81) {
        cst[243] = expf(lsl[0]);                                  // step_length
    } else if (tid == 82) {
        cst[244] = fmaxf(fr[0] * fr[0], 1e-10f) * (1.f / 65536.f); // reg_weight
    } else if (tid >= 83 && tid < 89) {
        cst[245 + (tid - 83)] = 0.f;                              // src[3], reg[3] accumulators
    }
}

// ---------------- copy flt input -> d_out ----------------
__global__ void k_copy(const float* __restrict__ src, float* __restrict__ dst) {
    int i = (blockIdx.x * 256 + threadIdx.x) * 4;
    st4(dst + i, ld4(src + i));
}

// ---------------- KA: scores = corr(flt, feat); elementwise; write mres, smask; src loss ----
__global__ __launch_bounds__(128) void ka_corr(const float* __restrict__ flt,
                                               const float* __restrict__ feat,
                                               const float* cst,
                                               float* __restrict__ mres,
                                               float* __restrict__ smask,
                                               float* lossacc, int it) {
    const int b = blockIdx.x >> 5, y = blockIdx.x & 31;
    const int tid = threadIdx.x;
    const bool active = tid < 72;
    const int x0 = tid & 7, dy = tid >> 3;  // dy in 0..8 for active

    float acc[9][4];
#pragma unroll
    for (int i = 0; i < 9; i++) { acc[i][0] = acc[i][1] = acc[i][2] = acc[i][3] = 0.f; }

    if (active) {
        const int ry = y + dy - 4;
        if (ry >= 0 && ry < 32) {
            const float* fp = flt  + ((b * NC) * NH + y) * NW + x0 * 4;
            const float* gp = feat + ((b * NC) * NH + ry) * NW + x0 * 4 - 4;
            const bool v0 = (x0 > 0), v2 = (x0 < 7);
#pragma unroll 2
            for (int c = 0; c < NC; c++) {
                float4 f = ld4(fp + c * 1024);
                float4 q0 = v0 ? ld4(gp + c * 1024)     : make_float4(0.f, 0.f, 0.f, 0.f);
                float4 q1 =      ld4(gp + c * 1024 + 4);
                float4 q2 = v2 ? ld4(gp + c * 1024 + 8) : make_float4(0.f, 0.f, 0.f, 0.f);
                float w[12] = {q0.x, q0.y, q0.z, q0.w, q1.x, q1.y, q1.z, q1.w,
                               q2.x, q2.y, q2.z, q2.w};
                float fv[4] = {f.x, f.y, f.z, f.w};
#pragma unroll
                for (int dx = 0; dx < 9; dx++)
#pragma unroll
                    for (int xi = 0; xi < 4; xi++)
                        acc[dx][xi] = fmaf(fv[xi], w[xi + dx], acc[dx][xi]);
            }
        }
    }

    float srcl = 0.f;
    if (active) {
#pragma unroll
        for (int dx = 0; dx < 9; dx++) {
            const int k = dy * 9 + dx;
            const float lab = cst[k], m = cst[81 + k], sw = cst[162 + k];
            const float am = 0.5f * (1.f - m), ap = 0.5f * (1.f + m);
            float tr[4], tm[4];
#pragma unroll
            for (int xi = 0; xi < 4; xi++) {
                float s = acc[dx][xi];
                float act = am * fabsf(s) + ap * s;
                float sgn = (s > 0.f ? 1.f : 0.f) - (s < 0.f ? 1.f : 0.f);
                float msk = am * sgn + ap;
                float lres = sw * (act - lab);
                srcl = fmaf(lres, lres, srcl);
                tr[xi] = msk * sw * lres;
                tm[xi] = msk;
            }
            int o = ((b * NK + k) * NH + y) * NW + x0 * 4;
            st4(mres + o,  make_float4(tr[0], tr[1], tr[2], tr[3]));
            st4(smask + o, make_float4(tm[0], tm[1], tm[2], tm[3]));
        }
    }
#pragma unroll
    for (int off = 32; off > 0; off >>= 1) srcl += __shfl_down(srcl, off, 64);
    if ((tid & 63) == 0) atomicAdd(lossacc + it, srcl);
}

// ---------------- KB: fg = corr_T(mres, feat) + rw*flt; alpha_num; reg loss ----------------
__global__ __launch_bounds__(256) void kb_grad(const float* __restrict__ flt,
                                               const float* __restrict__ feat,
                                               const float* __restrict__ mres,
                                               const float* cst,
                                               float* __restrict__ fg,
                                               float* __restrict__ anum,
                                               float* regacc, int it) {
    const int b = blockIdx.x >> 5, y = blockIdx.x & 31;
    const int tid = threadIdx.x;
    const int x0 = tid & 7, cslot = tid >> 3;
    const int cbase = cslot * 8;
    const float rw = cst[244];
    const bool v0 = (x0 > 0), v2 = (x0 < 7);

    float acc[8][4];
#pragma unroll
    for (int i = 0; i < 8; i++) { acc[i][0] = acc[i][1] = acc[i][2] = acc[i][3] = 0.f; }

    for (int dy = 0; dy < 9; dy++) {
        const int ry = y + dy - 4;
        if (ry < 0 || ry > 31) continue;  // block-uniform branch
        float rr[9][4];
#pragma unroll
        for (int dx = 0; dx < 9; dx++) {
            float4 t = ld4(mres + ((b * NK + dy * 9 + dx) * NH + y) * NW + x0 * 4);
            rr[dx][0] = t.x; rr[dx][1] = t.y; rr[dx][2] = t.z; rr[dx][3] = t.w;
        }
#pragma unroll
        for (int cc = 0; cc < 8; cc++) {
            const float* gp = feat + ((b * NC + cbase + cc) * NH + ry) * NW + x0 * 4 - 4;
            float4 q0 = v0 ? ld4(gp)     : make_float4(0.f, 0.f, 0.f, 0.f);
            float4 q1 =      ld4(gp + 4);
            float4 q2 = v2 ? ld4(gp + 8) : make_float4(0.f, 0.f, 0.f, 0.f);
            float w[12] = {q0.x, q0.y, q0.z, q0.w, q1.x, q1.y, q1.z, q1.w,
                           q2.x, q2.y, q2.z, q2.w};
#pragma unroll
            for (int dx = 0; dx < 9; dx++)
#pragma unroll
                for (int xi = 0; xi < 4; xi++)
                    acc[cc][xi] = fmaf(rr[dx][xi], w[xi + dx], acc[cc][xi]);
        }
    }

    __shared__ float red[32 * 33];
    float regl = 0.f;
    float an[4] = {0.f, 0.f, 0.f, 0.f};
#pragma unroll
    for (int cc = 0; cc < 8; cc++) {
        int o = ((b * NC + cbase + cc) * NH + y) * NW + x0 * 4;
        float4 fl = ld4(flt + o);
        float g0 = acc[cc][0] + rw * fl.x;
        float g1 = acc[cc][1] + rw * fl.y;
        float g2 = acc[cc][2] + rw * fl.z;
        float g3 = acc[cc][3] + rw * fl.w;
        st4(fg + o, make_float4(g0, g1, g2, g3));
        regl += fl.x * fl.x + fl.y * fl.y + fl.z * fl.z + fl.w * fl.w;
        an[0] += g0 * g0; an[1] += g1 * g1; an[2] += g2 * g2; an[3] += g3 * g3;
    }
#pragma unroll
    for (int xi = 0; xi < 4; xi++) red[(x0 * 4 + xi) * 33 + cslot] = an[xi];
    __syncthreads();
    if (tid < 32) {
        float s = 0.f;
#pragma unroll
        for (int cs = 0; cs < 32; cs++) s += red[tid * 33 + cs];
        anum[(b * NH + y) * NW + tid] = s;
    }
#pragma unroll
    for (int off = 32; off > 0; off >>= 1) regl += __shfl_down(regl, off, 64);
    if ((tid & 63) == 0) atomicAdd(regacc + it, regl);
}

// ---------------- KC: sg = corr(fg, feat)*sw*mask; alpha; flt update ----------------
__global__ __launch_bounds__(128) void kc_update(float* __restrict__ flt,
                                                 const float* __restrict__ feat,
                                                 const float* __restrict__ fg,
                                                 const float* __restrict__ smask,
                                                 const float* cst,
                                                 const float* __restrict__ anum) {
    const int b = blockIdx.x >> 5, y = blockIdx.x & 31;
    const int tid = threadIdx.x;
    const bool active = tid < 72;
    const int x0 = tid & 7, dy = tid >> 3;

    float acc[9][4];
#pragma unroll
    for (int i = 0; i < 9; i++) { acc[i][0] = acc[i][1] = acc[i][2] = acc[i][3] = 0.f; }

    if (active) {
        const int ry = y + dy - 4;
        if (ry >= 0 && ry < 32) {
            const float* fp = fg   + ((b * NC) * NH + y) * NW + x0 * 4;
            const float* gp = feat + ((b * NC) * NH + ry) * NW + x0 * 4 - 4;
            const bool v0 = (x0 > 0), v2 = (x0 < 7);
#pragma unroll 2
            for (int c = 0; c < NC; c++) {
                float4 f = ld4(fp + c * 1024);
                float4 q0 = v0 ? ld4(gp + c * 1024)     : make_float4(0.f, 0.f, 0.f, 0.f);
                float4 q1 =      ld4(gp + c * 1024 + 4);
                float4 q2 = v2 ? ld4(gp + c * 1024 + 8) : make_float4(0.f, 0.f, 0.f, 0.f);
                float w[12] = {q0.x, q0.y, q0.z, q0.w, q1.x, q1.y, q1.z, q1.w,
                               q2.x, q2.y, q2.z, q2.w};
                float fv[4] = {f.x, f.y, f.z, f.w};
#pragma unroll
                for (int dx = 0; dx < 9; dx++)
#pragma unroll
                    for (int xi = 0; xi < 4; xi++)
                        acc[dx][xi] = fmaf(fv[xi], w[xi + dx], acc[dx][xi]);
            }
        }
    }

    __shared__ float dred[9 * 32];   // [dy][x]
    if (active) {
        float den[4] = {0.f, 0.f, 0.f, 0.f};
#pragma unroll
        for (int dx = 0; dx < 9; dx++) {
            int k = dy * 9 + dx;
            float sw = cst[162 + k];
            float4 mk = ld4(smask + ((b * NK + k) * NH + y) * NW + x0 * 4);
            float s0 = sw * mk.x * acc[dx][0]; den[0] = fmaf(s0, s0, den[0]);
            float s1 = sw * mk.y * acc[dx][1]; den[1] = fmaf(s1, s1, den[1]);
            float s2 = sw * mk.z * acc[dx][2]; den[2] = fmaf(s2, s2, den[2]);
            float s3 = sw * mk.w * acc[dx][3]; den[3] = fmaf(s3, s3, den[3]);
        }
#pragma unroll
        for (int xi = 0; xi < 4; xi++) dred[dy * 32 + x0 * 4 + xi] = den[xi];
    }
    __syncthreads();
    __shared__ float alpha_s[32];
    if (tid < 32) {
        float d = 0.f;
#pragma unroll
        for (int dy2 = 0; dy2 < 9; dy2++) d += dred[dy2 * 32 + tid];
        float num = anum[(b * NH + y) * NW + tid];
        float dd = fmaxf(d + cst[244] * num, 1e-8f);
        alpha_s[tid] = cst[243] * num / dd;   // step_length * alpha
    }
    __syncthreads();

    for (int i = tid; i < 2048; i += 128) {
        int c = i >> 3, xq = i & 7;
        int o = ((b * NC + c) * NH + y) * NW + xq * 4;
        float4 fl = ld4(flt + o);
        float4 g  = ld4(fg + o);
        fl.x -= alpha_s[xq * 4 + 0] * g.x;
        fl.y -= alpha_s[xq * 4 + 1] * g.y;
        fl.z -= alpha_s[xq * 4 + 2] * g.z;
        fl.w -= alpha_s[xq * 4 + 3] * g.w;
        st4(flt + o, fl);
    }
}

// ---------------- tail: write tr, tr_src, tr_reg ----------------
__global__ void k_tail(const float* cst, float* out) {
    int i = threadIdx.x;
    if (i < 3) {
        float rw = cst[244];
        float src = 0.5f * cst[245 + i] / 16.f;
        float reg = 0.5f * rw * cst[248 + i] / 16.f;
        out[4194304 + i] = src + reg;
        out[4194307 + i] = src;
        out[4194310 + i] = reg;
    }
}

extern "C" void kernel_launch(void* const* d_in, const int* in_sizes, int n_in,
                              void* d_out, int out_size, void* d_ws, size_t ws_size,
                              hipStream_t stream) {
    (void)in_sizes; (void)n_in; (void)out_size; (void)ws_size;
    const float* flt_in = (const float*)d_in[0];
    const float* feat   = (const float*)d_in[1];
    const float* lw     = (const float*)d_in[2];
    const float* mw     = (const float*)d_in[3];
    const float* sww    = (const float*)d_in[4];
    const float* lsl    = (const float*)d_in[5];
    const float* fr     = (const float*)d_in[6];
    float* out = (float*)d_out;
    float* ws  = (float*)d_ws;

    float* fg    = ws + WS_FG;
    float* mres  = ws + WS_MRES;
    float* smask = ws + WS_SMASK;
    float* anum  = ws + WS_ANUM;
    float* cst   = ws + WS_CONST;

    k_const<<<1, 128, 0, stream>>>(lw, mw, sww, lsl, fr, cst);
    k_copy<<<4096, 256, 0, stream>>>(flt_in, out);

    for (int it = 0; it < 3; it++) {
        ka_corr<<<512, 128, 0, stream>>>(out, feat, cst, mres, smask, cst + 245, it);
        kb_grad<<<512, 256, 0, stream>>>(out, feat, mres, cst, fg, anum, cst + 248, it);
        kc_update<<<512, 128, 0, stream>>>(out, feat, fg, smask, cst, anum);
    }
    k_tail<<<1, 64, 0, stream>>>(cst, out);
}

// Round 2
// 711.376 us; speedup vs baseline: 1.4863x; 1.4863x over previous
//
#include <hip/hip_runtime.h>
#include <cstddef>

// ---------------- problem constants ----------------
#define NB 16      // batch
#define NC 256     // channels
#define NH 32
#define NW 32
#define NK 81      // 9x9 displacements

// workspace float offsets (identical layout to round 1 — proven to fit ws_size)
#define WS_FG      0u                         // [16,256,32,32]
#define WS_MRES    4194304u                   // [16,81,32,32]
#define WS_SMASK   5521408u                   // [16,81,32,32]
#define WS_ANUM    6848512u                   // [16,32,32]
#define WS_CONST   6864896u                   // label[81], m[81], sw[81], step, rw, src[3], reg[3]

__device__ __forceinline__ float4 ld4(const float* p) { return *reinterpret_cast<const float4*>(p); }
__device__ __forceinline__ void st4(float* p, float4 v) { *reinterpret_cast<float4*>(p) = v; }

// XCD-aware (b,y) mapping: 512 blocks, blockIdx&7 = XCD slot -> each XCD sees 2 batches
__device__ __forceinline__ void map_by(int bi, int& b, int& y) {
    int xcd = bi & 7, slot = bi >> 3;
    b = xcd * 2 + (slot >> 5);
    y = slot & 31;
}

// ---------------- constants / distance map ----------------
__global__ void k_const(const float* lw, const float* mw, const float* sww,
                        const float* lsl, const float* fr, float* cst) {
    int tid = threadIdx.x;
    if (tid < 81) {
        int dy = tid / 9, dx = tid % 9;
        float dist = sqrtf((float)((dy - 4) * (dy - 4) + (dx - 4) * (dx - 4)));
        float lab = 0.f, mm = 0.f, ss = 0.f;
        for (int d = 0; d < 10; d++) {
            float diff = dist * 2.f - (float)d;
            float bv = (d < 9) ? fmaxf(0.f, 1.f - fabsf(diff))
                               : fminf(fmaxf(1.f + diff, 0.f), 1.f);
            lab += bv * lw[d];
            mm  += bv * mw[d];
            ss  += bv * sww[d];
        }
        cst[tid]       = lab;
        cst[81 + tid]  = 1.f / (1.f + expf(-mm));
        cst[162 + tid] = ss;
    } else if (tid == 81) {
        cst[243] = expf(lsl[0]);                                   // step_length
    } else if (tid == 82) {
        cst[244] = fmaxf(fr[0] * fr[0], 1e-10f) * (1.f / 65536.f); // reg_weight
    } else if (tid >= 83 && tid < 89) {
        cst[245 + (tid - 83)] = 0.f;                               // src[3], reg[3]
    }
}

// ---------------- copy flt input -> d_out ----------------
__global__ void k_copy(const float* __restrict__ src, float* __restrict__ dst) {
    int i = (blockIdx.x * 256 + threadIdx.x) * 4;
    st4(dst + i, ld4(src + i));
}

// ---------------- KA: scores = corr(flt, feat); elementwise; mres, smask; src loss ----------
// 320 threads: 288 active = 4 cgroups x (9 dy x 8 xquads). LDS cross-group reduce.
__global__ __launch_bounds__(320) void ka_corr(const float* __restrict__ flt,
                                               const float* __restrict__ feat,
                                               const float* cst,
                                               float* __restrict__ mres,
                                               float* __restrict__ smask,
                                               float* lossacc, int it) {
    int b, y; map_by(blockIdx.x, b, y);
    const int tid = threadIdx.x;
    __shared__ float lds[72 * 149];

    const bool act = tid < 288;
    const int cg = tid / 72, r = tid % 72;
    const int x0 = r & 7, dy = r >> 3;

    float acc[9][4];
#pragma unroll
    for (int i = 0; i < 9; i++) { acc[i][0] = acc[i][1] = acc[i][2] = acc[i][3] = 0.f; }

    if (act) {
        const int ry = y + dy - 4;
        if (ry >= 0 && ry < 32) {
            const float* fp = flt  + ((b * NC + cg * 64) * NH + y) * NW + x0 * 4;
            const float* gp = feat + ((b * NC + cg * 64) * NH + ry) * NW + x0 * 4 - 4;
            const bool v0 = (x0 > 0), v2 = (x0 < 7);
#pragma unroll 4
            for (int c = 0; c < 64; c++) {
                float4 f = ld4(fp + c * 1024);
                float4 q0 = v0 ? ld4(gp + c * 1024)     : make_float4(0.f, 0.f, 0.f, 0.f);
                float4 q1 =      ld4(gp + c * 1024 + 4);
                float4 q2 = v2 ? ld4(gp + c * 1024 + 8) : make_float4(0.f, 0.f, 0.f, 0.f);
                float w[12] = {q0.x, q0.y, q0.z, q0.w, q1.x, q1.y, q1.z, q1.w,
                               q2.x, q2.y, q2.z, q2.w};
                float fv[4] = {f.x, f.y, f.z, f.w};
#pragma unroll
                for (int dx = 0; dx < 9; dx++)
#pragma unroll
                    for (int xi = 0; xi < 4; xi++)
                        acc[dx][xi] = fmaf(fv[xi], w[xi + dx], acc[dx][xi]);
            }
        }
        float* row = lds + r * 149 + cg * 36;
#pragma unroll
        for (int dx = 0; dx < 9; dx++)
#pragma unroll
            for (int xi = 0; xi < 4; xi++) row[dx * 4 + xi] = acc[dx][xi];
    }
    __syncthreads();

    float srcl = 0.f;
    if (tid < 72) {
        const int x0b = tid & 7, dyb = tid >> 3;
        const float* row = lds + tid * 149;
#pragma unroll
        for (int dx = 0; dx < 9; dx++) {
            const int k = dyb * 9 + dx;
            const float lab = cst[k], m = cst[81 + k], sw = cst[162 + k];
            const float am = 0.5f * (1.f - m), ap = 0.5f * (1.f + m);
            float tr[4], tm[4];
#pragma unroll
            for (int xi = 0; xi < 4; xi++) {
                float s = row[dx * 4 + xi] + row[36 + dx * 4 + xi]
                        + row[72 + dx * 4 + xi] + row[108 + dx * 4 + xi];
                float act_v = am * fabsf(s) + ap * s;
                float sgn = (s > 0.f ? 1.f : 0.f) - (s < 0.f ? 1.f : 0.f);
                float msk = am * sgn + ap;
                float lres = sw * (act_v - lab);
                srcl = fmaf(lres, lres, srcl);
                tr[xi] = msk * sw * lres;
                tm[xi] = msk;
            }
            int o = ((b * NK + k) * NH + y) * NW + x0b * 4;
            st4(mres + o,  make_float4(tr[0], tr[1], tr[2], tr[3]));
            st4(smask + o, make_float4(tm[0], tm[1], tm[2], tm[3]));
        }
    }
#pragma unroll
    for (int off = 32; off > 0; off >>= 1) srcl += __shfl_down(srcl, off, 64);
    if ((tid & 63) == 0) atomicAdd(lossacc + it, srcl);
}

// ---------------- KB: fg = corr_T(mres, feat) + rw*flt; alpha_num; reg loss --------------
// 512 threads: (x0 8) x (cslot 64), 4 channels per thread.
__global__ __launch_bounds__(512) void kb_grad(const float* __restrict__ flt,
                                               const float* __restrict__ feat,
                                               const float* __restrict__ mres,
                                               const float* cst,
                                               float* __restrict__ fg,
                                               float* __restrict__ anum,
                                               float* regacc, int it) {
    int b, y; map_by(blockIdx.x, b, y);
    const int tid = threadIdx.x;
    const int x0 = tid & 7, cs = tid >> 3;
    const float rw = cst[244];
    const bool v0 = (x0 > 0), v2 = (x0 < 7);

    float acc[4][4];
#pragma unroll
    for (int i = 0; i < 4; i++) { acc[i][0] = acc[i][1] = acc[i][2] = acc[i][3] = 0.f; }

    for (int dy = 0; dy < 9; dy++) {
        const int ry = y + dy - 4;
        if (ry < 0 || ry > 31) continue;  // block-uniform branch
        float rr[9][4];
#pragma unroll
        for (int dx = 0; dx < 9; dx++) {
            float4 t = ld4(mres + ((b * NK + dy * 9 + dx) * NH + y) * NW + x0 * 4);
            rr[dx][0] = t.x; rr[dx][1] = t.y; rr[dx][2] = t.z; rr[dx][3] = t.w;
        }
        const float* gbase = feat + ((b * NC + cs * 4) * NH + ry) * NW + x0 * 4 - 4;
#pragma unroll
        for (int cc = 0; cc < 4; cc++) {
            const float* gp = gbase + cc * 1024;
            float4 q0 = v0 ? ld4(gp)     : make_float4(0.f, 0.f, 0.f, 0.f);
            float4 q1 =      ld4(gp + 4);
            float4 q2 = v2 ? ld4(gp + 8) : make_float4(0.f, 0.f, 0.f, 0.f);
            float w[12] = {q0.x, q0.y, q0.z, q0.w, q1.x, q1.y, q1.z, q1.w,
                           q2.x, q2.y, q2.z, q2.w};
#pragma unroll
            for (int dx = 0; dx < 9; dx++)
#pragma unroll
                for (int xi = 0; xi < 4; xi++)
                    acc[cc][xi] = fmaf(rr[dx][xi], w[xi + dx], acc[cc][xi]);
        }
    }

    __shared__ float red[32 * 65];
    float regl = 0.f;
    float an[4] = {0.f, 0.f, 0.f, 0.f};
#pragma unroll
    for (int cc = 0; cc < 4; cc++) {
        int o = ((b * NC + cs * 4 + cc) * NH + y) * NW + x0 * 4;
        float4 fl = ld4(flt + o);
        float g0 = acc[cc][0] + rw * fl.x;
        float g1 = acc[cc][1] + rw * fl.y;
        float g2 = acc[cc][2] + rw * fl.z;
        float g3 = acc[cc][3] + rw * fl.w;
        st4(fg + o, make_float4(g0, g1, g2, g3));
        regl += fl.x * fl.x + fl.y * fl.y + fl.z * fl.z + fl.w * fl.w;
        an[0] += g0 * g0; an[1] += g1 * g1; an[2] += g2 * g2; an[3] += g3 * g3;
    }
#pragma unroll
    for (int xi = 0; xi < 4; xi++) red[(x0 * 4 + xi) * 65 + cs] = an[xi];
    __syncthreads();
    if (tid < 32) {
        float s = 0.f;
#pragma unroll
        for (int c2 = 0; c2 < 64; c2++) s += red[tid * 65 + c2];
        anum[(b * NH + y) * NW + tid] = s;
    }
#pragma unroll
    for (int off = 32; off > 0; off >>= 1) regl += __shfl_down(regl, off, 64);
    if ((tid & 63) == 0) atomicAdd(regacc + it, regl);
}

// ---------------- KC: sg = corr(fg, feat)*sw*mask; alpha; flt update ---------------------
__global__ __launch_bounds__(320) void kc_update(float* __restrict__ flt,
                                                 const float* __restrict__ feat,
                                                 const float* __restrict__ fg,
                                                 const float* __restrict__ smask,
                                                 const float* cst,
                                                 const float* __restrict__ anum) {
    int b, y; map_by(blockIdx.x, b, y);
    const int tid = threadIdx.x;
    __shared__ float lds[72 * 149];
    __shared__ float dred[288];
    __shared__ float alpha_s[32];

    const bool act = tid < 288;
    const int cg = tid / 72, r = tid % 72;
    const int x0 = r & 7, dy = r >> 3;

    float acc[9][4];
#pragma unroll
    for (int i = 0; i < 9; i++) { acc[i][0] = acc[i][1] = acc[i][2] = acc[i][3] = 0.f; }

    if (act) {
        const int ry = y + dy - 4;
        if (ry >= 0 && ry < 32) {
            const float* fp = fg   + ((b * NC + cg * 64) * NH + y) * NW + x0 * 4;
            const float* gp = feat + ((b * NC + cg * 64) * NH + ry) * NW + x0 * 4 - 4;
            const bool v0 = (x0 > 0), v2 = (x0 < 7);
#pragma unroll 4
            for (int c = 0; c < 64; c++) {
                float4 f = ld4(fp + c * 1024);
                float4 q0 = v0 ? ld4(gp + c * 1024)     : make_float4(0.f, 0.f, 0.f, 0.f);
                float4 q1 =      ld4(gp + c * 1024 + 4);
                float4 q2 = v2 ? ld4(gp + c * 1024 + 8) : make_float4(0.f, 0.f, 0.f, 0.f);
                float w[12] = {q0.x, q0.y, q0.z, q0.w, q1.x, q1.y, q1.z, q1.w,
                               q2.x, q2.y, q2.z, q2.w};
                float fv[4] = {f.x, f.y, f.z, f.w};
#pragma unroll
                for (int dx = 0; dx < 9; dx++)
#pragma unroll
                    for (int xi = 0; xi < 4; xi++)
                        acc[dx][xi] = fmaf(fv[xi], w[xi + dx], acc[dx][xi]);
            }
        }
        float* row = lds + r * 149 + cg * 36;
#pragma unroll
        for (int dx = 0; dx < 9; dx++)
#pragma unroll
            for (int xi = 0; xi < 4; xi++) row[dx * 4 + xi] = acc[dx][xi];
    }
    __syncthreads();

    if (tid < 72) {
        const int x0b = tid & 7, dyb = tid >> 3;
        const float* row = lds + tid * 149;
        float den[4] = {0.f, 0.f, 0.f, 0.f};
#pragma unroll
        for (int dx = 0; dx < 9; dx++) {
            const int k = dyb * 9 + dx;
            const float sw = cst[162 + k];
            float4 mk = ld4(smask + ((b * NK + k) * NH + y) * NW + x0b * 4);
            float mv[4] = {mk.x, mk.y, mk.z, mk.w};
#pragma unroll
            for (int xi = 0; xi < 4; xi++) {
                float s = row[dx * 4 + xi] + row[36 + dx * 4 + xi]
                        + row[72 + dx * 4 + xi] + row[108 + dx * 4 + xi];
                float sg = sw * mv[xi] * s;
                den[xi] = fmaf(sg, sg, den[xi]);
            }
        }
#pragma unroll
        for (int xi = 0; xi < 4; xi++) dred[dyb * 32 + x0b * 4 + xi] = den[xi];
    }
    __syncthreads();
    if (tid < 32) {
        float d = 0.f;
#pragma unroll
        for (int dy2 = 0; dy2 < 9; dy2++) d += dred[dy2 * 32 + tid];
        float num = anum[(b * NH + y) * NW + tid];
        float dd = fmaxf(d + cst[244] * num, 1e-8f);
        alpha_s[tid] = cst[243] * num / dd;   // step_length * alpha
    }
    __syncthreads();

    for (int i = tid; i < 2048; i += 320) {
        int c = i >> 3, xq = i & 7;
        int o = ((b * NC + c) * NH + y) * NW + xq * 4;
        float4 fl = ld4(flt + o);
        float4 g  = ld4(fg + o);
        fl.x -= alpha_s[xq * 4 + 0] * g.x;
        fl.y -= alpha_s[xq * 4 + 1] * g.y;
        fl.z -= alpha_s[xq * 4 + 2] * g.z;
        fl.w -= alpha_s[xq * 4 + 3] * g.w;
        st4(flt + o, fl);
    }
}

// ---------------- tail: write tr, tr_src, tr_reg ----------------
__global__ void k_tail(const float* cst, float* out) {
    int i = threadIdx.x;
    if (i < 3) {
        float rw = cst[244];
        float src = 0.5f * cst[245 + i] / 16.f;
        float reg = 0.5f * rw * cst[248 + i] / 16.f;
        out[4194304 + i] = src + reg;
        out[4194307 + i] = src;
        out[4194310 + i] = reg;
    }
}

extern "C" void kernel_launch(void* const* d_in, const int* in_sizes, int n_in,
                              void* d_out, int out_size, void* d_ws, size_t ws_size,
                              hipStream_t stream) {
    (void)in_sizes; (void)n_in; (void)out_size; (void)ws_size;
    const float* flt_in = (const float*)d_in[0];
    const float* feat   = (const float*)d_in[1];
    const float* lw     = (const float*)d_in[2];
    const float* mw     = (const float*)d_in[3];
    const float* sww    = (const float*)d_in[4];
    const float* lsl    = (const float*)d_in[5];
    const float* fr     = (const float*)d_in[6];
    float* out = (float*)d_out;
    float* ws  = (float*)d_ws;

    float* fg    = ws + WS_FG;
    float* mres  = ws + WS_MRES;
    float* smask = ws + WS_SMASK;
    float* anum  = ws + WS_ANUM;
    float* cst   = ws + WS_CONST;

    k_const<<<1, 128, 0, stream>>>(lw, mw, sww, lsl, fr, cst);
    k_copy<<<4096, 256, 0, stream>>>(flt_in, out);

    for (int it = 0; it < 3; it++) {
        ka_corr<<<512, 320, 0, stream>>>(out, feat, cst, mres, smask, cst + 245, it);
        kb_grad<<<512, 512, 0, stream>>>(out, feat, mres, cst, fg, anum, cst + 248, it);
        kc_update<<<512, 320, 0, stream>>>(out, feat, fg, smask, cst, anum);
    }
    k_tail<<<1, 64, 0, stream>>>(cst, out);
}

// Round 3
// 667.299 us; speedup vs baseline: 1.5844x; 1.0661x over previous
//
#include <hip/hip_runtime.h>
#include <cstddef>

// ---------------- problem constants ----------------
#define NB 16      // batch
#define NC 256     // channels
#define NH 32
#define NW 32
#define NK 81      // 9x9 displacements

// workspace float offsets
#define WS_FG      0u                         // [16,256,32,32]
#define WS_MRES    4194304u                   // [16,81,32,32]
#define WS_SMASK   5521408u                   // [16,81,32,32]
#define WS_ANUM    6848512u                   // [16,32,32]
#define WS_CONST   6864896u                   // label[81], m[81], sw[81], step, rw, src[3], reg[3]

__device__ __forceinline__ float4 ld4(const float* p) { return *reinterpret_cast<const float4*>(p); }
__device__ __forceinline__ void st4(float* p, float4 v) { *reinterpret_cast<float4*>(p) = v; }

// XCD-aware (b,y) mapping: 512 blocks, blockIdx&7 = XCD slot -> each XCD sees 2 batches
__device__ __forceinline__ void map_by(int bi, int& b, int& y) {
    int xcd = bi & 7, slot = bi >> 3;
    b = xcd * 2 + (slot >> 5);
    y = slot & 31;
}

// ---------------- constants / distance map ----------------
__global__ void k_const(const float* lw, const float* mw, const float* sww,
                        const float* lsl, const float* fr, float* cst) {
    int tid = threadIdx.x;
    if (tid < 81) {
        int dy = tid / 9, dx = tid % 9;
        float dist = sqrtf((float)((dy - 4) * (dy - 4) + (dx - 4) * (dx - 4)));
        float lab = 0.f, mm = 0.f, ss = 0.f;
        for (int d = 0; d < 10; d++) {
            float diff = dist * 2.f - (float)d;
            float bv = (d < 9) ? fmaxf(0.f, 1.f - fabsf(diff))
                               : fminf(fmaxf(1.f + diff, 0.f), 1.f);
            lab += bv * lw[d];
            mm  += bv * mw[d];
            ss  += bv * sww[d];
        }
        cst[tid]       = lab;
        cst[81 + tid]  = 1.f / (1.f + expf(-mm));
        cst[162 + tid] = ss;
    } else if (tid == 81) {
        cst[243] = expf(lsl[0]);                                   // step_length
    } else if (tid == 82) {
        cst[244] = fmaxf(fr[0] * fr[0], 1e-10f) * (1.f / 65536.f); // reg_weight
    } else if (tid >= 83 && tid < 89) {
        cst[245 + (tid - 83)] = 0.f;                               // src[3], reg[3]
    }
}

// ---------------- copy flt input -> d_out ----------------
__global__ void k_copy(const float* __restrict__ src, float* __restrict__ dst) {
    int i = (blockIdx.x * 256 + threadIdx.x) * 4;
    st4(dst + i, ld4(src + i));
}

// Core correlation accumulate for one thread: 32 channels (4-ch batches), window FMAs.
// fsrc staged in LDS as float4[2048] (c*8 + xq). Returns acc[9][4].
__device__ __forceinline__ void corr_body(const float4* __restrict__ flt_s4,
                                          const float* __restrict__ gp,  // feat base (x0*4-4), ry row
                                          int cbase, int x0, float acc[9][4]) {
    const bool v0 = (x0 > 0), v2 = (x0 < 7);
    const float4 zero = make_float4(0.f, 0.f, 0.f, 0.f);
    for (int t = 0; t < 8; ++t) {
        float4 q0[4], q1[4], q2[4], f[4];
#pragma unroll
        for (int cc = 0; cc < 4; cc++) {
            const float* g = gp + (t * 4 + cc) * 1024;
            q0[cc] = v0 ? ld4(g)     : zero;
            q1[cc] =      ld4(g + 4);
            q2[cc] = v2 ? ld4(g + 8) : zero;
        }
#pragma unroll
        for (int cc = 0; cc < 4; cc++) f[cc] = flt_s4[(cbase + t * 4 + cc) * 8 + x0];
#pragma unroll
        for (int cc = 0; cc < 4; cc++) {
            float w[12] = {q0[cc].x, q0[cc].y, q0[cc].z, q0[cc].w,
                           q1[cc].x, q1[cc].y, q1[cc].z, q1[cc].w,
                           q2[cc].x, q2[cc].y, q2[cc].z, q2[cc].w};
            float fv[4] = {f[cc].x, f[cc].y, f[cc].z, f[cc].w};
#pragma unroll
            for (int dx = 0; dx < 9; dx++)
#pragma unroll
                for (int xi = 0; xi < 4; xi++)
                    acc[dx][xi] = fmaf(fv[xi], w[xi + dx], acc[dx][xi]);
        }
    }
}

// Two-phase cross-group reduce into red[72*152]: groups 0-3 write, 4-7 accumulate.
__device__ __forceinline__ void reduce_groups(float* red, int cg, int r, float acc[9][4]) {
    if (cg < 4) {
        float* row = red + r * 152 + cg * 36;
#pragma unroll
        for (int dx = 0; dx < 9; dx++)
            st4(row + dx * 4, make_float4(acc[dx][0], acc[dx][1], acc[dx][2], acc[dx][3]));
    }
    __syncthreads();
    if (cg >= 4) {
        float* row = red + r * 152 + (cg - 4) * 36;
#pragma unroll
        for (int dx = 0; dx < 9; dx++) {
            float4 t = ld4(row + dx * 4);
            t.x += acc[dx][0]; t.y += acc[dx][1]; t.z += acc[dx][2]; t.w += acc[dx][3];
            st4(row + dx * 4, t);
        }
    }
    __syncthreads();
}

// ---------------- KA: scores = corr(flt, feat); elementwise; mres, smask; src loss ------
// 576 threads = 8 cgroups x (9 dy x 8 xq); 32 ch/thread; flt row staged in LDS.
__global__ __launch_bounds__(576) void ka_corr(const float* __restrict__ flt,
                                               const float* __restrict__ feat,
                                               const float* cst,
                                               float* __restrict__ mres,
                                               float* __restrict__ smask,
                                               float* lossacc, int it) {
    int b, y; map_by(blockIdx.x, b, y);
    const int tid = threadIdx.x;
    __shared__ float4 flt_s4[2048];     // [c][xq] 32 KB
    __shared__ float red[72 * 152];     // 43.8 KB

    const int cg = tid / 72, r = tid % 72;
    const int x0 = r & 7, dy = r >> 3;

    // stage flt(b, :, y, :) -> LDS
    {
        const float* base = flt + ((size_t)b * NC) * (NH * NW) + y * NW;
        for (int i = tid; i < 2048; i += 576) {
            int c = i >> 3, xq = i & 7;
            flt_s4[i] = ld4(base + c * (NH * NW) + xq * 4);
        }
    }
    __syncthreads();

    float acc[9][4];
#pragma unroll
    for (int i = 0; i < 9; i++) { acc[i][0] = acc[i][1] = acc[i][2] = acc[i][3] = 0.f; }

    const int ry = y + dy - 4;
    if (ry >= 0 && ry < 32) {
        const float* gp = feat + ((size_t)(b * NC + cg * 32) * NH + ry) * NW + x0 * 4 - 4;
        corr_body(flt_s4, gp, cg * 32, x0, acc);
    }
    reduce_groups(red, cg, r, acc);

    float srcl = 0.f;
    if (tid < 72) {
        const int x0b = tid & 7, dyb = tid >> 3;
        const float* row = red + tid * 152;
#pragma unroll
        for (int dx = 0; dx < 9; dx++) {
            const int k = dyb * 9 + dx;
            const float lab = cst[k], m = cst[81 + k], sw = cst[162 + k];
            const float am = 0.5f * (1.f - m), ap = 0.5f * (1.f + m);
            float tr[4], tm[4];
#pragma unroll
            for (int xi = 0; xi < 4; xi++) {
                float s = row[dx * 4 + xi] + row[36 + dx * 4 + xi]
                        + row[72 + dx * 4 + xi] + row[108 + dx * 4 + xi];
                float act_v = am * fabsf(s) + ap * s;
                float sgn = (s > 0.f ? 1.f : 0.f) - (s < 0.f ? 1.f : 0.f);
                float msk = am * sgn + ap;
                float lres = sw * (act_v - lab);
                srcl = fmaf(lres, lres, srcl);
                tr[xi] = msk * sw * lres;
                tm[xi] = msk;
            }
            int o = ((b * NK + k) * NH + y) * NW + x0b * 4;
            st4(mres + o,  make_float4(tr[0], tr[1], tr[2], tr[3]));
            st4(smask + o, make_float4(tm[0], tm[1], tm[2], tm[3]));
        }
    }
#pragma unroll
    for (int off = 32; off > 0; off >>= 1) srcl += __shfl_down(srcl, off, 64);
    if ((tid & 63) == 0) atomicAdd(lossacc + it, srcl);
}

// ---------------- KB: fg = corr_T(mres, feat) + rw*flt; alpha_num; reg loss --------------
// 512 threads: (x0 8) x (cslot 64), 4 channels per thread.
__global__ __launch_bounds__(512) void kb_grad(const float* __restrict__ flt,
                                               const float* __restrict__ feat,
                                               const float* __restrict__ mres,
                                               const float* cst,
                                               float* __restrict__ fg,
                                               float* __restrict__ anum,
                                               float* regacc, int it) {
    int b, y; map_by(blockIdx.x, b, y);
    const int tid = threadIdx.x;
    const int x0 = tid & 7, cs = tid >> 3;
    const float rw = cst[244];
    const bool v0 = (x0 > 0), v2 = (x0 < 7);

    float acc[4][4];
#pragma unroll
    for (int i = 0; i < 4; i++) { acc[i][0] = acc[i][1] = acc[i][2] = acc[i][3] = 0.f; }

    for (int dy = 0; dy < 9; dy++) {
        const int ry = y + dy - 4;
        if (ry < 0 || ry > 31) continue;  // block-uniform branch
        float rr[9][4];
#pragma unroll
        for (int dx = 0; dx < 9; dx++) {
            float4 t = ld4(mres + ((b * NK + dy * 9 + dx) * NH + y) * NW + x0 * 4);
            rr[dx][0] = t.x; rr[dx][1] = t.y; rr[dx][2] = t.z; rr[dx][3] = t.w;
        }
        const float* gbase = feat + ((size_t)(b * NC + cs * 4) * NH + ry) * NW + x0 * 4 - 4;
#pragma unroll
        for (int cc = 0; cc < 4; cc++) {
            const float* gp = gbase + cc * 1024;
            float4 q0 = v0 ? ld4(gp)     : make_float4(0.f, 0.f, 0.f, 0.f);
            float4 q1 =      ld4(gp + 4);
            float4 q2 = v2 ? ld4(gp + 8) : make_float4(0.f, 0.f, 0.f, 0.f);
            float w[12] = {q0.x, q0.y, q0.z, q0.w, q1.x, q1.y, q1.z, q1.w,
                           q2.x, q2.y, q2.z, q2.w};
#pragma unroll
            for (int dx = 0; dx < 9; dx++)
#pragma unroll
                for (int xi = 0; xi < 4; xi++)
                    acc[cc][xi] = fmaf(rr[dx][xi], w[xi + dx], acc[cc][xi]);
        }
    }

    __shared__ float red[32 * 65];
    float regl = 0.f;
    float an[4] = {0.f, 0.f, 0.f, 0.f};
#pragma unroll
    for (int cc = 0; cc < 4; cc++) {
        int o = ((b * NC + cs * 4 + cc) * NH + y) * NW + x0 * 4;
        float4 fl = ld4(flt + o);
        float g0 = acc[cc][0] + rw * fl.x;
        float g1 = acc[cc][1] + rw * fl.y;
        float g2 = acc[cc][2] + rw * fl.z;
        float g3 = acc[cc][3] + rw * fl.w;
        st4(fg + o, make_float4(g0, g1, g2, g3));
        regl += fl.x * fl.x + fl.y * fl.y + fl.z * fl.z + fl.w * fl.w;
        an[0] += g0 * g0; an[1] += g1 * g1; an[2] += g2 * g2; an[3] += g3 * g3;
    }
#pragma unroll
    for (int xi = 0; xi < 4; xi++) red[(x0 * 4 + xi) * 65 + cs] = an[xi];
    __syncthreads();
    if (tid < 32) {
        float s = 0.f;
#pragma unroll
        for (int c2 = 0; c2 < 64; c2++) s += red[tid * 65 + c2];
        anum[(b * NH + y) * NW + tid] = s;
    }
#pragma unroll
    for (int off = 32; off > 0; off >>= 1) regl += __shfl_down(regl, off, 64);
    if ((tid & 63) == 0) atomicAdd(regacc + it, regl);
}

// ---------------- KC: sg = corr(fg, feat)*sw*mask; alpha; flt update ---------------------
__global__ __launch_bounds__(576) void kc_update(float* __restrict__ flt,
                                                 const float* __restrict__ feat,
                                                 const float* __restrict__ fg,
                                                 const float* __restrict__ smask,
                                                 const float* cst,
                                                 const float* __restrict__ anum) {
    int b, y; map_by(blockIdx.x, b, y);
    const int tid = threadIdx.x;
    __shared__ float4 flt_s4[2048];     // fg row staged here
    __shared__ float red[72 * 152];
    __shared__ float dred[288];
    __shared__ float alpha_s[32];

    const int cg = tid / 72, r = tid % 72;
    const int x0 = r & 7, dy = r >> 3;

    // stage fg(b, :, y, :) -> LDS
    {
        const float* base = fg + ((size_t)b * NC) * (NH * NW) + y * NW;
        for (int i = tid; i < 2048; i += 576) {
            int c = i >> 3, xq = i & 7;
            flt_s4[i] = ld4(base + c * (NH * NW) + xq * 4);
        }
    }
    __syncthreads();

    float acc[9][4];
#pragma unroll
    for (int i = 0; i < 9; i++) { acc[i][0] = acc[i][1] = acc[i][2] = acc[i][3] = 0.f; }

    const int ry = y + dy - 4;
    if (ry >= 0 && ry < 32) {
        const float* gp = feat + ((size_t)(b * NC + cg * 32) * NH + ry) * NW + x0 * 4 - 4;
        corr_body(flt_s4, gp, cg * 32, x0, acc);
    }
    reduce_groups(red, cg, r, acc);

    if (tid < 72) {
        const int x0b = tid & 7, dyb = tid >> 3;
        const float* row = red + tid * 152;
        float den[4] = {0.f, 0.f, 0.f, 0.f};
#pragma unroll
        for (int dx = 0; dx < 9; dx++) {
            const int k = dyb * 9 + dx;
            const float sw = cst[162 + k];
            float4 mk = ld4(smask + ((b * NK + k) * NH + y) * NW + x0b * 4);
            float mv[4] = {mk.x, mk.y, mk.z, mk.w};
#pragma unroll
            for (int xi = 0; xi < 4; xi++) {
                float s = row[dx * 4 + xi] + row[36 + dx * 4 + xi]
                        + row[72 + dx * 4 + xi] + row[108 + dx * 4 + xi];
                float sg = sw * mv[xi] * s;
                den[xi] = fmaf(sg, sg, den[xi]);
            }
        }
#pragma unroll
        for (int xi = 0; xi < 4; xi++) dred[dyb * 32 + x0b * 4 + xi] = den[xi];
    }
    __syncthreads();
    if (tid < 32) {
        float d = 0.f;
#pragma unroll
        for (int dy2 = 0; dy2 < 9; dy2++) d += dred[dy2 * 32 + tid];
        float num = anum[(b * NH + y) * NW + tid];
        float dd = fmaxf(d + cst[244] * num, 1e-8f);
        alpha_s[tid] = cst[243] * num / dd;   // step_length * alpha
    }
    __syncthreads();

    for (int i = tid; i < 2048; i += 576) {
        int c = i >> 3, xq = i & 7;
        int o = ((b * NC + c) * NH + y) * NW + xq * 4;
        float4 fl = ld4(flt + o);
        float4 g  = flt_s4[i];   // fg row already in LDS
        fl.x -= alpha_s[xq * 4 + 0] * g.x;
        fl.y -= alpha_s[xq * 4 + 1] * g.y;
        fl.z -= alpha_s[xq * 4 + 2] * g.z;
        fl.w -= alpha_s[xq * 4 + 3] * g.w;
        st4(flt + o, fl);
    }
}

// ---------------- tail: write tr, tr_src, tr_reg ----------------
__global__ void k_tail(const float* cst, float* out) {
    int i = threadIdx.x;
    if (i < 3) {
        float rw = cst[244];
        float src = 0.5f * cst[245 + i] / 16.f;
        float reg = 0.5f * rw * cst[248 + i] / 16.f;
        out[4194304 + i] = src + reg;
        out[4194307 + i] = src;
        out[4194310 + i] = reg;
    }
}

extern "C" void kernel_launch(void* const* d_in, const int* in_sizes, int n_in,
                              void* d_out, int out_size, void* d_ws, size_t ws_size,
                              hipStream_t stream) {
    (void)in_sizes; (void)n_in; (void)out_size; (void)ws_size;
    const float* flt_in = (const float*)d_in[0];
    const float* feat   = (const float*)d_in[1];
    const float* lw     = (const float*)d_in[2];
    const float* mw     = (const float*)d_in[3];
    const float* sww    = (const float*)d_in[4];
    const float* lsl    = (const float*)d_in[5];
    const float* fr     = (const float*)d_in[6];
    float* out = (float*)d_out;
    float* ws  = (float*)d_ws;

    float* fg    = ws + WS_FG;
    float* mres  = ws + WS_MRES;
    float* smask = ws + WS_SMASK;
    float* anum  = ws + WS_ANUM;
    float* cst   = ws + WS_CONST;

    k_const<<<1, 128, 0, stream>>>(lw, mw, sww, lsl, fr, cst);
    k_copy<<<4096, 256, 0, stream>>>(flt_in, out);

    for (int it = 0; it < 3; it++) {
        ka_corr<<<512, 576, 0, stream>>>(out, feat, cst, mres, smask, cst + 245, it);
        kb_grad<<<512, 512, 0, stream>>>(out, feat, mres, cst, fg, anum, cst + 248, it);
        kc_update<<<512, 576, 0, stream>>>(out, feat, fg, smask, cst, anum);
    }
    k_tail<<<1, 64, 0, stream>>>(cst, out);
}